// Round 12
// baseline (767.938 us; speedup 1.0000x reference)
//
#include <hip/hip_runtime.h>
#include <math.h>

#define HW_ 65536
#define NCHUNK 16
typedef long long i64;
#define TWO_PI 6.283185307179586476925f

typedef __bf16 bf16x8 __attribute__((ext_vector_type(8)));
typedef __bf16 bf16x4 __attribute__((ext_vector_type(4)));
typedef float f32x4 __attribute__((ext_vector_type(4)));

#define MFMA16(A,B,C) __builtin_amdgcn_mfma_f32_16x16x32_bf16(A,B,C,0,0,0)

__device__ __forceinline__ float sigm(float x){ return 1.0f/(1.0f+expf(-x)); }

// convert 8 consecutive fp32 to a bf16x8 A-fragment
__device__ __forceinline__ bf16x8 cvt_w8(const float* wp){
  float4 w0 = *(const float4*)wp;
  float4 w1 = *(const float4*)(wp+4);
  bf16x8 r;
  r[0]=(__bf16)w0.x; r[1]=(__bf16)w0.y; r[2]=(__bf16)w0.z; r[3]=(__bf16)w0.w;
  r[4]=(__bf16)w1.x; r[5]=(__bf16)w1.y; r[6]=(__bf16)w1.z; r[7]=(__bf16)w1.w;
  return r;
}

__device__ __forceinline__ void st_bf4(__bf16* p, float a, float b, float c, float d){
  bf16x4 v; v[0]=(__bf16)a; v[1]=(__bf16)b; v[2]=(__bf16)c; v[3]=(__bf16)d;
  *(bf16x4*)p = v;
}

// bilinear resize sample (identical fp32 formula to the old k_resize)
__device__ __forceinline__ float rsz(const float* p, int yy, int xx){
  float sx = xx*0.5f - 0.25f;
  float sy = yy*0.5f - 0.25f;
  int x0 = (int)floorf(sx); float fx = sx - (float)x0;
  int y0 = (int)floorf(sy); float fy = sy - (float)y0;
  int x1 = min(x0+1,127); int y1 = min(y0+1,127);
  x0 = max(x0,0); y0 = max(y0,0);
  float v00=p[y0*128+x0], v01=p[y0*128+x1], v10=p[y1*128+x0], v11=p[y1*128+x1];
  return (1.0f-fy)*((1.0f-fx)*v00 + fx*v01) + fy*((1.0f-fx)*v10 + fx*v11);
}

// ---------------- fused resize + conv3x3 3->64 (bf16 out): block per (b,row) ----------------
__global__ __launch_bounds__(256) void k_conv3r(const float* __restrict__ x, const float* __restrict__ w,
                                                __bf16* __restrict__ out, int b0){
  int y = blockIdx.x & 255; int b = blockIdx.x >> 8; int t = threadIdx.x;
  float win[27];
  #pragma unroll
  for (int ci=0;ci<3;ci++){
    const float* xp = x + ((i64)((b0+b)*3 + ci))*16384;
    #pragma unroll
    for (int ky=0;ky<3;ky++){
      int yy = y+ky-1;
      #pragma unroll
      for (int kx=0;kx<3;kx++){
        int xx = t+kx-1;
        float v = 0.f;
        if ((unsigned)yy<256u && (unsigned)xx<256u) v = rsz(xp, yy, xx);
        win[ci*9+ky*3+kx] = v;
      }
    }
  }
  i64 obase = ((i64)b<<22) + (y<<8) + t;
  for (int o=0;o<64;o++){
    const float* wp = w + o*27;
    float acc=0.f;
    #pragma unroll
    for (int j=0;j<27;j++) acc += wp[j]*win[j];
    out[obase + ((i64)o<<16)] = (__bf16)acc;
  }
}

// ---------------- DFT coeffs (7 reals incl. DC) + pooled mean per (b,c), bf16 in ----------------
__global__ __launch_bounds__(256) void k_dft(const __bf16* __restrict__ xc, float* __restrict__ coeff, float* __restrict__ pooled){
  __shared__ float tc[256], ts[256];
  __shared__ float red[256];
  int t = threadIdx.x;
  float ang = TWO_PI * ((float)t/256.0f);
  tc[t] = cosf(ang); ts[t] = sinf(ang);
  __syncthreads();
  int bc = blockIdx.x;
  const __bf16* p = xc + (i64)bc*HW_;
  float s=0, cr=0, ci=0, rr=0, ri=0, dr=0, di=0;
  for (int i=t; i<HW_; i+=256){
    float v = (float)p[i];
    int col = i & 255, row = i >> 8, ds = (row+col)&255;
    s  += v;
    cr += v*tc[col]; ci += v*ts[col];
    rr += v*tc[row]; ri += v*ts[row];
    dr += v*tc[ds];  di += v*ts[ds];
  }
  float vals[7] = {s,cr,ci,rr,ri,dr,di};
  for (int j=0;j<7;j++){
    red[t] = vals[j]; __syncthreads();
    for (int st=128; st>0; st>>=1){ if (t<st) red[t]+=red[t+st]; __syncthreads(); }
    if (t==0) vals[j] = red[0];
    __syncthreads();
  }
  if (t==0){
    const float sc = 1.0f/65536.0f;
    for (int j=0;j<7;j++) coeff[bc*8+j] = vals[j]*sc;
    pooled[bc] = vals[0]*sc;
  }
}

// ---------------- threshold MLP -> per-batch mask flag ----------------
__global__ __launch_bounds__(64) void k_thr(const float* __restrict__ pooled, const float* __restrict__ w1,
                      const float* __restrict__ w2, float* __restrict__ flag){
  __shared__ float hid[8];
  int b = blockIdx.x; int t = threadIdx.x;
  if (t < 8){
    float a = 0.f;
    for (int c=0;c<64;c++) a += pooled[b*64+c]*w1[t*64+c];
    hid[t] = 0.5f*a*(1.0f+erff(a*0.70710678118654752440f));
  }
  __syncthreads();
  if (t==0){
    float t0=0,t1=0;
    for (int k=0;k<8;k++){ t0 += hid[k]*w2[k]; t1 += hid[k]*w2[8+k]; }
    int h_ = (int)(2.0f*sigm(t0));
    int w_ = (int)(2.0f*sigm(t1));
    flag[b] = (h_>0 && w_>0) ? 1.0f : 0.0f;
  }
}

#define MM_SETUP \
  int t = threadIdx.x; \
  int lane = t & 63, wvi = t >> 6; \
  i64 px0 = (i64)blockIdx.x*256 + wvi*64; \
  int b = (int)(px0 >> 16); \
  int p0 = (int)(px0 & (HW_-1)); \
  i64 ibase = ((i64)b<<22) + p0; \
  int lm = lane & 15, kg = lane >> 4;

// =====================================================================================
// X8 MM family: 8 px/lane, 128 px/wave, 16B loads+stores, per-m acc (32 VGPR).
// =====================================================================================
#define X8_SETUP_BLK(BLK) \
  int t = threadIdx.x; \
  int lane = t & 63, wvi = t >> 6; \
  i64 px0 = (i64)(BLK)*512 + (i64)wvi*128; \
  int b = (int)(px0 >> 16); \
  int p0 = (int)(px0 & (HW_-1)); \
  i64 ibase = ((i64)b<<22) + p0; \
  int lm = lane & 15, kg = lane >> 4;

#define X8_SETUP X8_SETUP_BLK(blockIdx.x)

#define X8_FILL_F32(in_ptr) \
  _Pragma("unroll") \
  for (int s=0;s<2;s++){ \
    _Pragma("unroll") \
    for (int j=0;j<8;j++){ \
      const float* p_ = (in_ptr) + ((i64)(s*32 + kg*8 + j)<<16) + 8*lm; \
      float4 a_ = *(const float4*)p_; \
      float4 c_ = *(const float4*)(p_+4); \
      bf[s][0][j]=(__bf16)a_.x; bf[s][1][j]=(__bf16)a_.y; bf[s][2][j]=(__bf16)a_.z; bf[s][3][j]=(__bf16)a_.w; \
      bf[s][4][j]=(__bf16)c_.x; bf[s][5][j]=(__bf16)c_.y; bf[s][6][j]=(__bf16)c_.z; bf[s][7][j]=(__bf16)c_.w; \
    } \
  }

#define X8_FILL_BF(in_ptr) \
  _Pragma("unroll") \
  for (int s=0;s<2;s++){ \
    _Pragma("unroll") \
    for (int j=0;j<8;j++){ \
      bf16x8 u_ = *(const bf16x8*)((in_ptr) + ((i64)(s*32 + kg*8 + j)<<16) + 8*lm); \
      _Pragma("unroll") \
      for (int e=0;e<8;e++) bf[s][e][j] = u_[e]; \
    } \
  }

#define X8_ACC_M(Wbase, BF) \
  bf16x8 af0 = cvt_w8((Wbase) + (m*16 + lm)*64 + kg*8); \
  bf16x8 af1 = cvt_w8((Wbase) + (m*16 + lm)*64 + 32 + kg*8); \
  f32x4 acc[8]; \
  _Pragma("unroll") \
  for (int e=0;e<8;e++){ f32x4 z_ = {0.f,0.f,0.f,0.f}; acc[e]=z_; } \
  _Pragma("unroll") \
  for (int e=0;e<8;e++){ acc[e]=MFMA16(af0,BF[0][e],acc[e]); acc[e]=MFMA16(af1,BF[1][e],acc[e]); }

#define X8_ST_BF(outp) \
  _Pragma("unroll") \
  for (int r=0;r<4;r++){ \
    int oc = m*16 + kg*4 + r; \
    bf16x8 ov; \
    _Pragma("unroll") \
    for (int e=0;e<8;e++) ov[e]=(__bf16)acc[e][r]; \
    *(bf16x8*)((outp) + ibase + ((i64)oc<<16) + 8*lm) = ov; \
  }

#define X8_MM_BF(Wbase, BF, outp) \
  _Pragma("unroll") \
  for (int m=0;m<4;m++){ X8_ACC_M(Wbase, BF) X8_ST_BF(outp) }

// ---------------- fused: DFT recon (shared) -> BOTH high & low conv1x1 ----------------
__global__ __launch_bounds__(256) void k_convq2(const __bf16* __restrict__ xc, const float* __restrict__ coeff,
      const float* __restrict__ flag, const float* __restrict__ qwh, const float* __restrict__ qwl,
      __bf16* __restrict__ outh, __bf16* __restrict__ outl){
  __shared__ float tc[256], ts[256];
  {
    int tt = threadIdx.x;
    float ang = TWO_PI * ((float)tt/256.0f);
    tc[tt]=cosf(ang); ts[tt]=sinf(ang);
  }
  __syncthreads();
  MM_SETUP
  float fl = flag[b];
  int y = p0 >> 8;
  int xb = (p0 & 255) + 4*lm;
  bf16x8 bfh[2][4], bfl[2][4];
  {
    float crow = tc[y], srow = ts[y];
    float cx[4], sx[4], cd[4], sd[4];
    #pragma unroll
    for (int e=0;e<4;e++){
      int xx = xb + e;
      cx[e]=tc[xx]; sx[e]=ts[xx];
      int d = (xx + y) & 255;
      cd[e]=tc[d]; sd[e]=ts[d];
    }
    #pragma unroll
    for (int s=0;s<2;s++){
      #pragma unroll
      for (int j=0;j<8;j++){
        int ch = s*32 + kg*8 + j;
        const float* cf = coeff + ((b<<6)+ch)*8;
        float4 ca = *(const float4*)cf;
        float4 cb = *(const float4*)(cf+4);
        float F00=ca.x, cR=ca.y, cI=ca.z, rR=ca.w, rI=cb.x, dR=cb.y, dI=cb.z;
        bf16x4 xr4 = *(const bf16x4*)(xc + ibase + ((i64)ch<<16) + 4*lm);
        float rowR = F00 + rR*crow + rI*srow;
        float rowI = rI*crow - rR*srow;
        #pragma unroll
        for (int e=0;e<4;e++){
          float re = rowR + cR*cx[e] + cI*sx[e] + dR*cd[e] + dI*sd[e];
          float im = rowI + cI*cx[e] - cR*sx[e] + dI*cd[e] - dR*sd[e];
          re*=fl; im*=fl;
          float vl = sqrtf(re*re+im*im);
          float hr = (float)xr4[e] - re;
          float vh = sqrtf(hr*hr + im*im);
          bfh[s][e][j] = (__bf16)vh;
          bfl[s][e][j] = (__bf16)vl;
        }
      }
    }
  }
  // high path, per-m acc
  #pragma unroll
  for (int m=0;m<4;m++){
    bf16x8 af0 = cvt_w8(qwh + (m*16 + lm)*64 + kg*8);
    bf16x8 af1 = cvt_w8(qwh + (m*16 + lm)*64 + 32 + kg*8);
    f32x4 acc[4];
    #pragma unroll
    for (int e=0;e<4;e++){ f32x4 z={0.f,0.f,0.f,0.f}; acc[e]=z; }
    #pragma unroll
    for (int e=0;e<4;e++){ acc[e]=MFMA16(af0,bfh[0][e],acc[e]); acc[e]=MFMA16(af1,bfh[1][e],acc[e]); }
    #pragma unroll
    for (int r=0;r<4;r++){
      int oc = m*16 + kg*4 + r;
      st_bf4(outh + ibase + ((i64)oc<<16) + 4*lm, acc[0][r], acc[1][r], acc[2][r], acc[3][r]);
    }
  }
  // low path, per-m acc
  #pragma unroll
  for (int m=0;m<4;m++){
    bf16x8 af0 = cvt_w8(qwl + (m*16 + lm)*64 + kg*8);
    bf16x8 af1 = cvt_w8(qwl + (m*16 + lm)*64 + 32 + kg*8);
    f32x4 acc[4];
    #pragma unroll
    for (int e=0;e<4;e++){ f32x4 z={0.f,0.f,0.f,0.f}; acc[e]=z; }
    #pragma unroll
    for (int e=0;e<4;e++){ acc[e]=MFMA16(af0,bfl[0][e],acc[e]); acc[e]=MFMA16(af1,bfl[1][e],acc[e]); }
    #pragma unroll
    for (int r=0;r<4;r++){
      int oc = m*16 + kg*4 + r;
      st_bf4(outl + ibase + ((i64)oc<<16) + 4*lm, acc[0][r], acc[1][r], acc[2][r], acc[3][r]);
    }
  }
}

// ---------------- fused conv1x1 from y (X8): kv0, kv1, q2 -- one y read ----------------
__global__ __launch_bounds__(256) void k_kvq(const float* __restrict__ yin,
      const float* __restrict__ kvw0, const float* __restrict__ kvw1, const float* __restrict__ qw2,
      __bf16* __restrict__ k0o, __bf16* __restrict__ v0o,
      __bf16* __restrict__ k1o, __bf16* __restrict__ v1o, __bf16* __restrict__ q2o){
  X8_SETUP
  bf16x8 bf[2][8];
  X8_FILL_F32(yin + ibase)
  X8_MM_BF(kvw0,        bf, k0o)
  X8_MM_BF(kvw0 + 4096, bf, v0o)
  X8_MM_BF(kvw1,        bf, k1o)
  X8_MM_BF(kvw1 + 4096, bf, v1o)
  X8_MM_BF(qw2,         bf, q2o)
}

// ---------------- fused sw(7x7) + comb + refine conv1x1 + kv2 conv1x1 ----------------
// sw computed per-block into LDS (same loop order as old k_sw -> identical fp32);
// agg round-trips through LDS only (bit-identical to global agg).
__global__ __launch_bounds__(256) void k_comb_kvb(const __bf16* __restrict__ lo2, const __bf16* __restrict__ hi2,
        const float* __restrict__ mxm, const float* __restrict__ mnm, const float* __restrict__ spw,
        const float* __restrict__ cwv,
        const float* __restrict__ w, const float* __restrict__ bias,
        const float* __restrict__ wkv,
        __bf16* __restrict__ kout, __bf16* __restrict__ vout){
  __shared__ __bf16 aggl[64][514];    // [ch][block-local px], +2 px pad
  __shared__ float swl[512];
  X8_SETUP
  int pxl = wvi*128 + 8*lm;           // block-local px base for this lane
  // --- sw: 7x7 conv over mx/mn for this block's 512 px (rows base_row, base_row+1)
  {
    int base_row = p0 >> 8;           // p0 of wave 0 == block base; rows = blk*2, blk*2+1 within batch
    // recompute block base row from block px range: block covers px [blockIdx*512 mod HW)
    int blk_p0 = (int)(((i64)blockIdx.x*512) & (HW_-1));
    base_row = blk_p0 >> 8;
    const float* m0 = mxm + ((i64)b<<16);
    const float* m1 = mnm + ((i64)b<<16);
    #pragma unroll
    for (int half=0; half<2; half++){
      int q = t + half*256;
      int row = base_row + (q >> 8);
      int col = q & 255;
      float acc=0.f;
      for (int ky=0;ky<7;ky++){
        int yy = row+ky-3; if ((unsigned)yy>255u) continue;
        for (int kx=0;kx<7;kx++){
          int xx = col+kx-3; if ((unsigned)xx>255u) continue;
          acc += spw[ky*7+kx]*m0[yy*256+xx] + spw[49+ky*7+kx]*m1[yy*256+xx];
        }
      }
      swl[q] = sigm(acc);
    }
  }
  __syncthreads();
  float swv[8];
  #pragma unroll
  for (int e=0;e<8;e++) swv[e] = swl[pxl+e];
  bf16x8 bf[2][8];
  #pragma unroll
  for (int s=0;s<2;s++){
    #pragma unroll
    for (int j=0;j<8;j++){
      int ch = s*32 + kg*8 + j;
      bf16x8 l8 = *(const bf16x8*)(lo2 + ibase + ((i64)ch<<16) + 8*lm);
      bf16x8 h8 = *(const bf16x8*)(hi2 + ibase + ((i64)ch<<16) + 8*lm);
      float cw = cwv[(b<<6) + ch];
      #pragma unroll
      for (int e=0;e<8;e++) bf[s][e][j] = (__bf16)((float)l8[e]*swv[e] + (float)h8[e]*cw);
    }
  }
  #pragma unroll
  for (int m=0;m<4;m++){
    X8_ACC_M(w, bf)
    #pragma unroll
    for (int r=0;r<4;r++){
      int oc = m*16 + kg*4 + r;
      float bv = bias[oc];
      bf16x8 ov;
      #pragma unroll
      for (int e=0;e<8;e++) ov[e]=(__bf16)(acc[e][r]+bv);
      *(bf16x8*)(&aggl[oc][pxl]) = ov;
    }
  }
  __syncthreads();
  // rebuild B-frags from LDS agg (same wave's px, all 64 ch)
  bf16x8 bf2[2][8];
  #pragma unroll
  for (int s=0;s<2;s++){
    #pragma unroll
    for (int j=0;j<8;j++){
      int ch = s*32 + kg*8 + j;
      bf16x8 u_ = *(const bf16x8*)(&aggl[ch][pxl]);
      #pragma unroll
      for (int e=0;e<8;e++) bf2[s][e][j] = u_[e];
    }
  }
  X8_MM_BF(wkv,        bf2, kout)
  X8_MM_BF(wkv + 4096, bf2, vout)
}

// ---------------- merged mconv hi + lo (double-grid) ----------------
__global__ __launch_bounds__(256) void k_mm_hilo(const __bf16* __restrict__ va, const __bf16* __restrict__ vb,
        const float* __restrict__ M0, const float* __restrict__ M1,
        float* __restrict__ mx, float* __restrict__ mn,
        __bf16* __restrict__ outa, __bf16* __restrict__ outb,
        float* __restrict__ spart, int hgrid){
  __shared__ float ls[4][64], lmx[4][64];
  int bx = blockIdx.x;
  int set = (bx >= hgrid) ? 1 : 0;
  int blk = bx - set*hgrid;
  X8_SETUP_BLK(blk)
  if (set == 0){
    // hi: M0 x va + per-px channel max/mean
    bf16x8 bf[2][8];
    X8_FILL_BF(va + ibase)
    const float* Wb = M0 + ((i64)b<<12);
    float smx[8], ssum[8];
    #pragma unroll
    for (int e=0;e<8;e++){ smx[e]=-1e30f; ssum[e]=0.f; }
    #pragma unroll
    for (int m=0;m<4;m++){
      X8_ACC_M(Wb, bf)
      X8_ST_BF(outa)
      #pragma unroll
      for (int r=0;r<4;r++){
        #pragma unroll
        for (int e=0;e<8;e++){ smx[e]=fmaxf(smx[e],acc[e][r]); ssum[e]+=acc[e][r]; }
      }
    }
    #pragma unroll
    for (int e=0;e<8;e++){
      smx[e] = fmaxf(smx[e], __shfl_xor(smx[e],16));
      smx[e] = fmaxf(smx[e], __shfl_xor(smx[e],32));
      ssum[e] += __shfl_xor(ssum[e],16);
      ssum[e] += __shfl_xor(ssum[e],32);
    }
    if (kg==0){
      i64 pbase = ((i64)b<<16) + p0 + 8*lm;
      *(float4*)(mx+pbase)   = make_float4(smx[0],smx[1],smx[2],smx[3]);
      *(float4*)(mx+pbase+4) = make_float4(smx[4],smx[5],smx[6],smx[7]);
      const float iv = 1.0f/64.0f;
      *(float4*)(mn+pbase)   = make_float4(ssum[0]*iv,ssum[1]*iv,ssum[2]*iv,ssum[3]*iv);
      *(float4*)(mn+pbase+4) = make_float4(ssum[4]*iv,ssum[5]*iv,ssum[6]*iv,ssum[7]*iv);
    }
  } else {
    // lo: M1 x vb + per-channel sum/max partials
    bf16x8 bf[2][8];
    X8_FILL_BF(vb + ibase)
    const float* Wb = M1 + ((i64)b<<12);
    #pragma unroll
    for (int m=0;m<4;m++){
      X8_ACC_M(Wb, bf)
      X8_ST_BF(outb)
      #pragma unroll
      for (int r=0;r<4;r++){
        int oc = m*16 + kg*4 + r;
        float s = 0.f, mm = -1e30f;
        #pragma unroll
        for (int e=0;e<8;e++){ s += acc[e][r]; mm = fmaxf(mm, acc[e][r]); }
        #pragma unroll
        for (int off=8; off; off>>=1){ s += __shfl_xor(s,off); mm = fmaxf(mm,__shfl_xor(mm,off)); }
        if (lm==0){ ls[wvi][oc]=s; lmx[wvi][oc]=mm; }
      }
    }
    __syncthreads();
    if (t<64){
      float s = ls[0][t]+ls[1][t]+ls[2][t]+ls[3][t];
      float mm = fmaxf(fmaxf(lmx[0][t],lmx[1][t]),fmaxf(lmx[2][t],lmx[3][t]));
      spart[(i64)blk*128 + t*2]   = s;
      spart[(i64)blk*128 + t*2+1] = mm;
    }
  }
}

// ---------------- final mconv (X8): M x v, *para1 + y*para2, fp32 out ----------------
__global__ __launch_bounds__(256) void k_mm_fin(const __bf16* __restrict__ v, const float* __restrict__ M,
      const float* __restrict__ para1, const float* __restrict__ para2,
      const float* __restrict__ yin, float* __restrict__ out){
  X8_SETUP
  bf16x8 bf[2][8];
  X8_FILL_BF(v + ibase)
  const float* Wb = M + ((i64)b<<12);
  #pragma unroll
  for (int m=0;m<4;m++){
    X8_ACC_M(Wb, bf)
    #pragma unroll
    for (int r=0;r<4;r++){
      int oc = m*16 + kg*4 + r;
      float p1 = para1[oc], p2 = para2[oc];
      const float* yp = yin + ibase + ((i64)oc<<16) + 8*lm;
      float4 y0 = *(const float4*)yp;
      float4 y1 = *(const float4*)(yp+4);
      float* op = out + ibase + ((i64)oc<<16) + 8*lm;
      *(float4*)op     = make_float4(acc[0][r]*p1+y0.x*p2, acc[1][r]*p1+y0.y*p2,
                                     acc[2][r]*p1+y0.z*p2, acc[3][r]*p1+y0.w*p2);
      *(float4*)(op+4) = make_float4(acc[4][r]*p1+y1.x*p2, acc[5][r]*p1+y1.y*p2,
                                     acc[6][r]*p1+y1.z*p2, acc[7][r]*p1+y1.w*p2);
    }
  }
}

// ---------------- Gram-MFMA stats w/ LDS 2-row staging, merged double-set dispatch ----------------
__global__ __launch_bounds__(256) void k_gram(const __bf16* __restrict__ q0, const __bf16* __restrict__ kk0,
        const __bf16* __restrict__ q1, const __bf16* __restrict__ kk1,
        const float* __restrict__ qdw0, const float* __restrict__ kdw0,
        const float* __restrict__ qdw1, const float* __restrict__ kdw1,
        float* __restrict__ part, int hgrid){
  __shared__ __bf16 lds[2][2][16][264];
  __shared__ float red[4][16][16];
  int bx = blockIdx.x;
  int set = (bx >= hgrid) ? 1 : 0;
  int blk = bx - set*hgrid;
  const __bf16* qpre = set ? q1 : q0;
  const __bf16* kpre = set ? kk1 : kk0;
  const float* qdw = set ? qdw1 : qdw0;
  const float* kdw = set ? kdw1 : kdw0;
  float* ppart = part + (i64)set*hgrid*80;
  int rowblk = blk & 15;
  int bh = blk >> 4;
  int h = bh & 7, b = bh >> 3;
  int t = threadIdx.x;
  int lane = t & 63, wvi = t >> 6;
  int lm = lane & 15, kg = lane >> 4;
  const float* wp = (lm < 8 ? qdw : kdw) + h*72 + (lm&7)*9;
  float w0=wp[0],w1=wp[1],w2=wp[2],w3=wp[3],w4=wp[4],w5=wp[5],w6=wp[6],w7=wp[7],w8=wp[8];
  int p = t >> 4, seg = t & 15;
  const __bf16* plbase = (p < 8 ? qpre : kpre) + (((i64)((b<<6)+(h<<3)+(p&7)))<<16);
  int R0 = rowblk*16;

  float h0c[2][8], h1c[2][8];
  #pragma unroll
  for (int cc=0;cc<2;cc++)
    #pragma unroll
    for (int e=0;e<8;e++){ h0c[cc][e]=0.f; h1c[cc][e]=0.f; }
  f32x4 acc = {0.f,0.f,0.f,0.f};

  auto stage2 = [&](int bi, int ir){
    #pragma unroll
    for (int rr=0;rr<2;rr++){
      int r_ = ir + rr;
      __bf16* dst = &lds[bi][rr][p][seg*16];
      if ((unsigned)r_ < 256u){
        const __bf16* src = plbase + r_*256 + seg*16;
        bf16x8 a = *(const bf16x8*)src;
        bf16x8 c = *(const bf16x8*)(src+8);
        *(bf16x8*)dst = a; *(bf16x8*)(dst+8) = c;
      } else {
        bf16x8 z = {};
        *(bf16x8*)dst = z; *(bf16x8*)(dst+8) = z;
      }
    }
  };

  stage2(0, R0-1);
  __syncthreads();
  int buf = 0;
  for (int pr = 0; pr < 9; pr++){
    int irbase = R0-1 + 2*pr;
    if (pr < 8) stage2(buf^1, irbase+2);
    #pragma unroll
    for (int rr=0;rr<2;rr++){
      int ir = irbase + rr;
      const __bf16* rowp = &lds[buf][rr][lm][0];
      #pragma unroll
      for (int cc=0; cc<2; cc++){
        int xb = (wvi*2 + cc)*32 + kg*8;
        bf16x8 mid = *(const bf16x8*)(rowp + xb);
        float win[10];
        win[0] = (xb==0)   ? 0.f : (float)rowp[xb-1];
        #pragma unroll
        for (int w=1; w<9; w++) win[w] = (float)mid[w-1];
        win[9] = (xb==248) ? 0.f : (float)rowp[xb+8];
        float o[8];
        #pragma unroll
        for (int e=0;e<8;e++){
          float t0 = w0*win[e] + w1*win[e+1] + w2*win[e+2];
          float t1 = w3*win[e] + w4*win[e+1] + w5*win[e+2];
          float t2 = w6*win[e] + w7*win[e+1] + w8*win[e+2];
          o[e] = h0c[cc][e] + t2;
          h0c[cc][e] = h1c[cc][e] + t1;
          h1c[cc][e] = t0;
        }
        if (ir > R0){
          bf16x8 xf;
          #pragma unroll
          for (int e=0;e<8;e++) xf[e] = (__bf16)o[e];
          acc = MFMA16(xf, xf, acc);
        }
      }
    }
    __syncthreads();
    buf ^= 1;
  }
  #pragma unroll
  for (int r=0;r<4;r++) red[wvi][kg*4+r][lm] = acc[r];
  __syncthreads();
  if (t < 80){
    int r, c;
    if (t < 64){ r = t>>3; c = 8 + (t&7); }
    else if (t < 72){ r = t-64; c = r; }
    else { r = 8 + (t-72); c = r; }
    float s = red[0][r][c]+red[1][r][c]+red[2][r][c]+red[3][r][c];
    ppart[(i64)blk*80 + t] = s;
  }
}

// ---------------- softmax + fold attn into 64x64 M (inline part reduction; 2-set super-b) ----------------
__global__ __launch_bounds__(64) void k_attn_m(const float* __restrict__ part, const float* __restrict__ temp,
                         const float* __restrict__ projw, float* __restrict__ M, int nb){
  __shared__ float stl[8][80];
  __shared__ float attn[8][8][8];
  int bsup = blockIdx.x; int t = threadIdx.x;
  int set = (bsup >= nb) ? 1 : 0;
  // inline stats_fin: reduce NCHUNK part-chunks (same c-order as old k_stats_fin)
  for (int v = t; v < 640; v += 64){
    int hh = v/80, j = v - hh*80;
    i64 bh = (i64)bsup*8 + hh;
    float s=0.f;
    for (int c=0;c<NCHUNK;c++) s += part[(bh*NCHUNK+c)*80 + j];
    stl[hh][j] = s;
  }
  __syncthreads();
  int h = t >> 3, cc = t & 7;
  const float* st = stl[h];
  float nq = fmaxf(sqrtf(st[64+cc]), 1e-12f);
  float tmp = temp[set*8 + h];
  const float* pw = projw + set*4096;
  float s[8];
  float mx = -1e30f;
  #pragma unroll
  for (int d=0;d<8;d++){
    float nk = fmaxf(sqrtf(st[72+d]), 1e-12f);
    s[d] = st[cc*8+d]/(nq*nk)*tmp;
    mx = fmaxf(mx, s[d]);
  }
  float sum=0.f;
  #pragma unroll
  for (int d=0;d<8;d++){ s[d]=expf(s[d]-mx); sum+=s[d]; }
  float inv = 1.0f/sum;
  #pragma unroll
  for (int d=0;d<8;d++) attn[h][cc][d] = s[d]*inv;
  __syncthreads();
  int o = t;
  for (int hh=0; hh<8; hh++){
    #pragma unroll
    for (int d=0; d<8; d++){
      float acc=0.f;
      #pragma unroll
      for (int c2=0;c2<8;c2++) acc += pw[o*64 + hh*8 + c2]*attn[hh][c2][d];
      M[((i64)bsup*64 + o)*64 + hh*8 + d] = acc;
    }
  }
}

// ---------------- depthwise 3x3 (v path), merged double-set dispatch ----------------
__global__ __launch_bounds__(256) void k_dwb(const __bf16* __restrict__ in0, const __bf16* __restrict__ in1,
        const float* __restrict__ wd0, const float* __restrict__ wd1,
        __bf16* __restrict__ out0, __bf16* __restrict__ out1, int hgrid){
  int bx = blockIdx.x;
  int set = (bx >= hgrid) ? 1 : 0;
  int blk = bx - set*hgrid;
  const __bf16* in = set ? in1 : in0;
  const float* wd = set ? wd1 : wd0;
  __bf16* out = set ? out1 : out0;
  int half = blk & 1; int c = (blk>>1)&63; int b = blk>>7;
  int t = threadIdx.x;
  int strip = t & 31, rg = t >> 5;
  const __bf16* ip = in + (((i64)((b<<6)+c))<<16);
  __bf16* op = out + (((i64)((b<<6)+c))<<16);
  const float* wp = wd + c*9;
  float w0=wp[0],w1=wp[1],w2=wp[2],w3=wp[3],w4=wp[4],w5=wp[5],w6=wp[6],w7=wp[7],w8=wp[8];
  int R0 = half*128 + rg*16;
  int xb = strip*8;
  bool left = (xb==0), right = (xb==248);
  float h0[8], h1[8];
  #pragma unroll
  for (int e=0;e<8;e++){ h0[e]=0.f; h1[e]=0.f; }
  for (int ir = R0-1; ir <= R0+16; ir++){
    bool rok = ((unsigned)ir < 256u);
    float win[10];
    if (rok){
      const __bf16* rp = ip + ir*256 + xb;
      bf16x8 mid = *(const bf16x8*)rp;
      win[0] = left ? 0.f : (float)rp[-1];
      #pragma unroll
      for (int w=1; w<9; w++) win[w] = (float)mid[w-1];
      win[9] = right ? 0.f : (float)rp[8];
    } else {
      #pragma unroll
      for (int w=0; w<10; w++) win[w] = 0.f;
    }
    float o[8];
    #pragma unroll
    for (int e=0;e<8;e++){
      float t0 = w0*win[e] + w1*win[e+1] + w2*win[e+2];
      float t1 = w3*win[e] + w4*win[e+1] + w5*win[e+2];
      float t2 = w6*win[e] + w7*win[e+1] + w8*win[e+2];
      o[e] = h0[e] + t2;
      h0[e] = h1[e] + t1;
      h1[e] = t0;
    }
    if (ir > R0){
      bf16x8 ov;
      #pragma unroll
      for (int e=0;e<8;e++) ov[e] = (__bf16)o[e];
      *(bf16x8*)(op + (ir-1)*256 + xb) = ov;
    }
  }
}

// ---------------- fused spatfin + cw: per-batch channel stats reduce + gate MLP ----------------
__global__ __launch_bounds__(64) void k_spatcw(const float* __restrict__ spart,
                     const float* __restrict__ w1, const float* __restrict__ w2, float* __restrict__ cw){
  __shared__ float lm_[64], lx_[64];
  __shared__ float ha[4], hm[4];
  int b = blockIdx.x; int c = threadIdx.x;
  float s=0.f, m=-1e30f;
  for (int r=0;r<128;r++){
    s += spart[(i64)(b*128+r)*128 + c*2];
    m = fmaxf(m, spart[(i64)(b*128+r)*128 + c*2+1]);
  }
  lm_[c] = s*(1.0f/65536.0f);
  lx_[c] = m;
  __syncthreads();
  if (c < 4){
    float sa=0.f, sm_=0.f;
    for (int j=0;j<64;j++){ sa += w1[c*64+j]*lm_[j]; sm_ += w1[c*64+j]*lx_[j]; }
    ha[c] = fmaxf(sa, 0.f); hm[c] = fmaxf(sm_, 0.f);
  }
  __syncthreads();
  float a=0.f;
  #pragma unroll
  for (int j=0;j<4;j++) a += w2[c*4+j]*(ha[j]+hm[j]);
  cw[b*64+c] = sigm(a);
}

// =====================================================================================
extern "C" void kernel_launch(void* const* d_in, const int* in_sizes, int n_in,
                              void* d_out, int out_size, void* d_ws, size_t ws_size,
                              hipStream_t stream){
  const float* x      = (const float*)d_in[0];
  const float* y      = (const float*)d_in[1];
  const float* conv1w = (const float*)d_in[2];
  const float* ratew1 = (const float*)d_in[3];
  const float* ratew2 = (const float*)d_in[4];
  const float* temp   = (const float*)d_in[5];
  const float* qw     = (const float*)d_in[6];
  const float* qdw    = (const float*)d_in[7];
  const float* kvw    = (const float*)d_in[8];
  const float* kvdw   = (const float*)d_in[9];
  const float* projw  = (const float*)d_in[10];
  const float* spw    = (const float*)d_in[11];
  const float* cgw1   = (const float*)d_in[12];
  const float* cgw2   = (const float*)d_in[13];
  const float* rprojw = (const float*)d_in[14];
  const float* rprojb = (const float*)d_in[15];
  const float* para1  = (const float*)d_in[16];
  const float* para2  = (const float*)d_in[17];
  float* D = (float*)d_out;

  // pick largest batch-group size whose footprint fits: 3 big units + pool
  int nb = 8;
  for (;;){
    size_t unit = (size_t)nb*64*HW_;
    size_t pool = (size_t)nb*512 + (size_t)nb*64 + 64
                + 2*(size_t)nb*8*NCHUNK*80    // part (2 sets)
                + 2*(size_t)nb*64*64          // M (2 sets)
                + 2*(size_t)nb*HW_            // mxmap, mnmap
                + (size_t)nb*128*128          // spart
                + (size_t)nb*64;              // cwb
    if ((3*unit + pool)*sizeof(float) <= ws_size || nb==1) break;
    nb >>= 1;
  }

  size_t unit = (size_t)nb*64*HW_;
  float* U0 = (float*)d_ws;
  float* U1 = U0 + unit;
  float* U2 = U1 + unit;
  float* sm = U2 + unit;
  float* coeff = sm;  sm += (size_t)nb*512;
  float* pooled= sm;  sm += (size_t)nb*64;
  float* flagb = sm;  sm += 64;
  float* part  = sm;  sm += 2*(size_t)nb*8*NCHUNK*80;
  float* Mb    = sm;  sm += 2*(size_t)nb*64*64;
  float* mxmap = sm;  sm += (size_t)nb*HW_;
  float* mnmap = sm;  sm += (size_t)nb*HW_;
  float* spart = sm;  sm += (size_t)nb*128*128;
  float* cwb   = sm;  sm += (size_t)nb*64;

  int hgr = nb*8*NCHUNK;     // gram half-grid
  int hdw = nb*128;          // dwb half-grid
  int hmm = nb*128;          // X8 half-grid

  for (int b0 = 0; b0 < 8; b0 += nb){
    const float* yg = y + (i64)b0*64*HW_;
    float*       Dg = D + (i64)b0*64*HW_;
    // bf16 tensor slots: each fp32 unit region holds TWO bf16 tensors of `unit` elements.
    __bf16* U0a = (__bf16*)U0; __bf16* U0c = U0a + unit;
    __bf16* U1a = (__bf16*)U1; __bf16* U1c = U1a + unit;
    __bf16* U2a = (__bf16*)U2; __bf16* U2c = U2a + unit;
    __bf16* Dga = (__bf16*)Dg; __bf16* Dgc = Dga + unit;
    float* Mb1 = Mb + (i64)nb*4096;

    // frontend (fused resize+conv3; xc bf16 in U0a)
    k_conv3r <<<nb*256,   256,0,stream>>>(x, conv1w, U0a, b0);         // xc = U0a (bf16)
    k_dft    <<<nb*64,    256,0,stream>>>(U0a, coeff, pooled);
    k_thr    <<<nb,       64, 0,stream>>>(pooled, ratew1, ratew2, flagb);

    // fused q-recon (cca0-high + cca1-low); xc dead after
    k_convq2 <<<nb*256,256,0,stream>>>(U0a, coeff, flagb, qw + 0*4096, qw + 1*4096, U1a, U1c); // qh=U1a, ql=U1c
    // fused y-matmuls (X8): kv0, kv1, q2-pre
    k_kvq    <<<nb*128,256,0,stream>>>(yg, kvw + 0*8192, kvw + 1*8192, qw + 2*4096,
                                       U2a, Dga, U2c, Dgc, U0c);       // k0,v0,k1,v1,q2

    // merged cca0+cca1 stats pipeline
    k_gram   <<<2*hgr,256,0,stream>>>(U1a, U2a, U1c, U2c,
                                      qdw + 0*576, kvdw + 0*1152, qdw + 1*576, kvdw + 1*1152,
                                      part, hgr);                      // [qh,ql,k0,k1 dead]
    k_dwb    <<<2*hdw,256,0,stream>>>(Dga, Dgc, kvdw + 0*1152 + 576, kvdw + 1*1152 + 576,
                                      U1a, U1c, hdw);                  // v0'=U1a, v1'=U1c [v0,v1 dead]
    k_attn_m <<<2*nb, 64,0,stream>>>(part, temp, projw, Mb, nb);       // Mb0, Mb1 (inline stats reduce)

    // merged hi+lo
    k_mm_hilo<<<2*hmm,256,0,stream>>>(U1a, U1c, Mb, Mb1, mxmap, mnmap, Dga, Dgc, spart, hmm);
                                                                       // high2=Dga, low2=Dgc

    // refine channel gate
    k_spatcw  <<<nb,     64, 0,stream>>>(spart, cgw1, cgw2, cwb);

    // fused sw + comb + refine-proj + kv2 (agg via LDS, never global)
    k_comb_kvb<<<nb*128,256,0,stream>>>(Dgc, Dga, mxmap, mnmap, spw, cwb, rprojw, rprojb,
                                        kvw + 2*8192, U2a, U2c);       // k2=U2a, v2=U2c

    // cca2 (q2=U0c)
    k_gram   <<<hgr,256,0,stream>>>(U0c, U2a, U0c, U2a,
                                    qdw + 2*576, kvdw + 2*1152, qdw + 2*576, kvdw + 2*1152,
                                    part, hgr);
    k_dwb    <<<hdw,256,0,stream>>>(U2c, U2c, kvdw + 2*1152 + 576, kvdw + 2*1152 + 576,
                                    U1a, U1a, hdw);                    // v'=U1a
    k_attn_m <<<nb, 64,0,stream>>>(part, temp + 2*8, projw + 2*4096, Mb, nb);
    k_mm_fin <<<nb*128,256,0,stream>>>(U1a, Mb, para1, para2, yg, Dg); // out fp32
  }
}

// Round 13
// 735.099 us; speedup vs baseline: 1.0447x; 1.0447x over previous
//
#include <hip/hip_runtime.h>
#include <math.h>

#define HW_ 65536
#define NCHUNK 16
typedef long long i64;
#define TWO_PI 6.283185307179586476925f

typedef __bf16 bf16x8 __attribute__((ext_vector_type(8)));
typedef __bf16 bf16x4 __attribute__((ext_vector_type(4)));
typedef float f32x4 __attribute__((ext_vector_type(4)));

#define MFMA16(A,B,C) __builtin_amdgcn_mfma_f32_16x16x32_bf16(A,B,C,0,0,0)

__device__ __forceinline__ float sigm(float x){ return 1.0f/(1.0f+expf(-x)); }

// convert 8 consecutive fp32 to a bf16x8 A-fragment
__device__ __forceinline__ bf16x8 cvt_w8(const float* wp){
  float4 w0 = *(const float4*)wp;
  float4 w1 = *(const float4*)(wp+4);
  bf16x8 r;
  r[0]=(__bf16)w0.x; r[1]=(__bf16)w0.y; r[2]=(__bf16)w0.z; r[3]=(__bf16)w0.w;
  r[4]=(__bf16)w1.x; r[5]=(__bf16)w1.y; r[6]=(__bf16)w1.z; r[7]=(__bf16)w1.w;
  return r;
}

__device__ __forceinline__ void st_bf4(__bf16* p, float a, float b, float c, float d){
  bf16x4 v; v[0]=(__bf16)a; v[1]=(__bf16)b; v[2]=(__bf16)c; v[3]=(__bf16)d;
  *(bf16x4*)p = v;
}

// ---------------- resize (nb,3,128,128) -> (nb,3,256,256) bilinear half-pixel ----------------
__global__ __launch_bounds__(256) void k_resize(const float* __restrict__ x, float* __restrict__ R, int b0){
  int idx = blockIdx.x*256 + threadIdx.x;
  int ox = idx & 255;
  int oy = (idx >> 8) & 255;
  int bc = idx >> 16;                               // lb*3 + c
  int lb = bc/3; int c = bc - lb*3;
  float sx = ox*0.5f - 0.25f;
  float sy = oy*0.5f - 0.25f;
  int x0 = (int)floorf(sx); float fx = sx - (float)x0;
  int y0 = (int)floorf(sy); float fy = sy - (float)y0;
  int x1 = min(x0+1,127); int y1 = min(y0+1,127);
  x0 = max(x0,0); y0 = max(y0,0);
  const float* p = x + ((i64)(b0+lb)*3 + c)*16384;
  float v00=p[y0*128+x0], v01=p[y0*128+x1], v10=p[y1*128+x0], v11=p[y1*128+x1];
  R[idx] = (1.0f-fy)*((1.0f-fx)*v00 + fx*v01) + fy*((1.0f-fx)*v10 + fx*v11);
}

// ---------------- conv3x3 3->64 (bf16 out): block per (b,row), all 64 outs per thread ----------------
__global__ __launch_bounds__(256) void k_conv3(const float* __restrict__ R, const float* __restrict__ w, __bf16* __restrict__ out){
  int y = blockIdx.x & 255; int b = blockIdx.x >> 8; int t = threadIdx.x;
  float win[27];
  #pragma unroll
  for (int ci=0;ci<3;ci++){
    #pragma unroll
    for (int ky=0;ky<3;ky++){
      int yy = y+ky-1;
      const float* ip = R + (((i64)(b*3+ci))<<16) + yy*256;
      #pragma unroll
      for (int kx=0;kx<3;kx++){
        int xx = t+kx-1;
        float v = 0.f;
        if ((unsigned)yy<256u && (unsigned)xx<256u) v = ip[xx];
        win[ci*9+ky*3+kx] = v;
      }
    }
  }
  i64 obase = ((i64)b<<22) + (y<<8) + t;
  for (int o=0;o<64;o++){
    const float* wp = w + o*27;
    float acc=0.f;
    #pragma unroll
    for (int j=0;j<27;j++) acc += wp[j]*win[j];
    out[obase + ((i64)o<<16)] = (__bf16)acc;
  }
}

// ---------------- DFT coeffs (7 reals incl. DC) + pooled mean per (b,c), bf16 in ----------------
__global__ __launch_bounds__(256) void k_dft(const __bf16* __restrict__ xc, float* __restrict__ coeff, float* __restrict__ pooled){
  __shared__ float tc[256], ts[256];
  __shared__ float red[256];
  int t = threadIdx.x;
  float ang = TWO_PI * ((float)t/256.0f);
  tc[t] = cosf(ang); ts[t] = sinf(ang);
  __syncthreads();
  int bc = blockIdx.x;
  const __bf16* p = xc + (i64)bc*HW_;
  float s=0, cr=0, ci=0, rr=0, ri=0, dr=0, di=0;
  for (int i=t; i<HW_; i+=256){
    float v = (float)p[i];
    int col = i & 255, row = i >> 8, ds = (row+col)&255;
    s  += v;
    cr += v*tc[col]; ci += v*ts[col];
    rr += v*tc[row]; ri += v*ts[row];
    dr += v*tc[ds];  di += v*ts[ds];
  }
  float vals[7] = {s,cr,ci,rr,ri,dr,di};
  for (int j=0;j<7;j++){
    red[t] = vals[j]; __syncthreads();
    for (int st=128; st>0; st>>=1){ if (t<st) red[t]+=red[t+st]; __syncthreads(); }
    if (t==0) vals[j] = red[0];
    __syncthreads();
  }
  if (t==0){
    const float sc = 1.0f/65536.0f;
    for (int j=0;j<7;j++) coeff[bc*8+j] = vals[j]*sc;
    pooled[bc] = vals[0]*sc;
  }
}

// ---------------- threshold MLP -> per-batch mask flag ----------------
__global__ __launch_bounds__(64) void k_thr(const float* __restrict__ pooled, const float* __restrict__ w1,
                      const float* __restrict__ w2, float* __restrict__ flag){
  __shared__ float hid[8];
  int b = blockIdx.x; int t = threadIdx.x;
  if (t < 8){
    float a = 0.f;
    for (int c=0;c<64;c++) a += pooled[b*64+c]*w1[t*64+c];
    hid[t] = 0.5f*a*(1.0f+erff(a*0.70710678118654752440f));
  }
  __syncthreads();
  if (t==0){
    float t0=0,t1=0;
    for (int k=0;k<8;k++){ t0 += hid[k]*w2[k]; t1 += hid[k]*w2[8+k]; }
    int h_ = (int)(2.0f*sigm(t0));
    int w_ = (int)(2.0f*sigm(t1));
    flag[b] = (h_>0 && w_>0) ? 1.0f : 0.0f;
  }
}

#define MM_SETUP \
  int t = threadIdx.x; \
  int lane = t & 63, wvi = t >> 6; \
  i64 px0 = (i64)blockIdx.x*256 + wvi*64; \
  int b = (int)(px0 >> 16); \
  int p0 = (int)(px0 & (HW_-1)); \
  i64 ibase = ((i64)b<<22) + p0; \
  int lm = lane & 15, kg = lane >> 4;

// =====================================================================================
// X8 MM family: 8 px/lane, 128 px/wave, 16B loads+stores, per-m acc (32 VGPR).
// =====================================================================================
#define X8_SETUP_BLK(BLK) \
  int t = threadIdx.x; \
  int lane = t & 63, wvi = t >> 6; \
  i64 px0 = (i64)(BLK)*512 + (i64)wvi*128; \
  int b = (int)(px0 >> 16); \
  int p0 = (int)(px0 & (HW_-1)); \
  i64 ibase = ((i64)b<<22) + p0; \
  int lm = lane & 15, kg = lane >> 4;

#define X8_SETUP X8_SETUP_BLK(blockIdx.x)

#define X8_FILL_F32(in_ptr) \
  _Pragma("unroll") \
  for (int s=0;s<2;s++){ \
    _Pragma("unroll") \
    for (int j=0;j<8;j++){ \
      const float* p_ = (in_ptr) + ((i64)(s*32 + kg*8 + j)<<16) + 8*lm; \
      float4 a_ = *(const float4*)p_; \
      float4 c_ = *(const float4*)(p_+4); \
      bf[s][0][j]=(__bf16)a_.x; bf[s][1][j]=(__bf16)a_.y; bf[s][2][j]=(__bf16)a_.z; bf[s][3][j]=(__bf16)a_.w; \
      bf[s][4][j]=(__bf16)c_.x; bf[s][5][j]=(__bf16)c_.y; bf[s][6][j]=(__bf16)c_.z; bf[s][7][j]=(__bf16)c_.w; \
    } \
  }

#define X8_FILL_BF(in_ptr) \
  _Pragma("unroll") \
  for (int s=0;s<2;s++){ \
    _Pragma("unroll") \
    for (int j=0;j<8;j++){ \
      bf16x8 u_ = *(const bf16x8*)((in_ptr) + ((i64)(s*32 + kg*8 + j)<<16) + 8*lm); \
      _Pragma("unroll") \
      for (int e=0;e<8;e++) bf[s][e][j] = u_[e]; \
    } \
  }

#define X8_ACC_M(Wbase, BF) \
  bf16x8 af0 = cvt_w8((Wbase) + (m*16 + lm)*64 + kg*8); \
  bf16x8 af1 = cvt_w8((Wbase) + (m*16 + lm)*64 + 32 + kg*8); \
  f32x4 acc[8]; \
  _Pragma("unroll") \
  for (int e=0;e<8;e++){ f32x4 z_ = {0.f,0.f,0.f,0.f}; acc[e]=z_; } \
  _Pragma("unroll") \
  for (int e=0;e<8;e++){ acc[e]=MFMA16(af0,BF[0][e],acc[e]); acc[e]=MFMA16(af1,BF[1][e],acc[e]); }

#define X8_ST_BF(outp) \
  _Pragma("unroll") \
  for (int r=0;r<4;r++){ \
    int oc = m*16 + kg*4 + r; \
    bf16x8 ov; \
    _Pragma("unroll") \
    for (int e=0;e<8;e++) ov[e]=(__bf16)acc[e][r]; \
    *(bf16x8*)((outp) + ibase + ((i64)oc<<16) + 8*lm) = ov; \
  }

#define X8_MM_BF(Wbase, BF, outp) \
  _Pragma("unroll") \
  for (int m=0;m<4;m++){ X8_ACC_M(Wbase, BF) X8_ST_BF(outp) }

// ---------------- fused: DFT recon (shared) -> BOTH high & low conv1x1 ----------------
// Per-m accumulator scoping (acc[4] live instead of acc[4][4]x2): VGPR ~224 -> ~130.
__global__ __launch_bounds__(256) void k_convq2(const __bf16* __restrict__ xc, const float* __restrict__ coeff,
      const float* __restrict__ flag, const float* __restrict__ qwh, const float* __restrict__ qwl,
      __bf16* __restrict__ outh, __bf16* __restrict__ outl){
  __shared__ float tc[256], ts[256];
  {
    int tt = threadIdx.x;
    float ang = TWO_PI * ((float)tt/256.0f);
    tc[tt]=cosf(ang); ts[tt]=sinf(ang);
  }
  __syncthreads();
  MM_SETUP
  float fl = flag[b];
  int y = p0 >> 8;
  int xb = (p0 & 255) + 4*lm;
  bf16x8 bfh[2][4], bfl[2][4];
  {
    float crow = tc[y], srow = ts[y];
    float cx[4], sx[4], cd[4], sd[4];
    #pragma unroll
    for (int e=0;e<4;e++){
      int xx = xb + e;
      cx[e]=tc[xx]; sx[e]=ts[xx];
      int d = (xx + y) & 255;
      cd[e]=tc[d]; sd[e]=ts[d];
    }
    #pragma unroll
    for (int s=0;s<2;s++){
      #pragma unroll
      for (int j=0;j<8;j++){
        int ch = s*32 + kg*8 + j;
        const float* cf = coeff + ((b<<6)+ch)*8;
        float4 ca = *(const float4*)cf;
        float4 cb = *(const float4*)(cf+4);
        float F00=ca.x, cR=ca.y, cI=ca.z, rR=ca.w, rI=cb.x, dR=cb.y, dI=cb.z;
        bf16x4 xr4 = *(const bf16x4*)(xc + ibase + ((i64)ch<<16) + 4*lm);
        float rowR = F00 + rR*crow + rI*srow;
        float rowI = rI*crow - rR*srow;
        #pragma unroll
        for (int e=0;e<4;e++){
          float re = rowR + cR*cx[e] + cI*sx[e] + dR*cd[e] + dI*sd[e];
          float im = rowI + cI*cx[e] - cR*sx[e] + dI*cd[e] - dR*sd[e];
          re*=fl; im*=fl;
          float vl = sqrtf(re*re+im*im);
          float hr = (float)xr4[e] - re;
          float vh = sqrtf(hr*hr + im*im);
          bfh[s][e][j] = (__bf16)vh;
          bfl[s][e][j] = (__bf16)vl;
        }
      }
    }
  }
  // high path, per-m acc
  #pragma unroll
  for (int m=0;m<4;m++){
    bf16x8 af0 = cvt_w8(qwh + (m*16 + lm)*64 + kg*8);
    bf16x8 af1 = cvt_w8(qwh + (m*16 + lm)*64 + 32 + kg*8);
    f32x4 acc[4];
    #pragma unroll
    for (int e=0;e<4;e++){ f32x4 z={0.f,0.f,0.f,0.f}; acc[e]=z; }
    #pragma unroll
    for (int e=0;e<4;e++){ acc[e]=MFMA16(af0,bfh[0][e],acc[e]); acc[e]=MFMA16(af1,bfh[1][e],acc[e]); }
    #pragma unroll
    for (int r=0;r<4;r++){
      int oc = m*16 + kg*4 + r;
      st_bf4(outh + ibase + ((i64)oc<<16) + 4*lm, acc[0][r], acc[1][r], acc[2][r], acc[3][r]);
    }
  }
  // low path, per-m acc
  #pragma unroll
  for (int m=0;m<4;m++){
    bf16x8 af0 = cvt_w8(qwl + (m*16 + lm)*64 + kg*8);
    bf16x8 af1 = cvt_w8(qwl + (m*16 + lm)*64 + 32 + kg*8);
    f32x4 acc[4];
    #pragma unroll
    for (int e=0;e<4;e++){ f32x4 z={0.f,0.f,0.f,0.f}; acc[e]=z; }
    #pragma unroll
    for (int e=0;e<4;e++){ acc[e]=MFMA16(af0,bfl[0][e],acc[e]); acc[e]=MFMA16(af1,bfl[1][e],acc[e]); }
    #pragma unroll
    for (int r=0;r<4;r++){
      int oc = m*16 + kg*4 + r;
      st_bf4(outl + ibase + ((i64)oc<<16) + 4*lm, acc[0][r], acc[1][r], acc[2][r], acc[3][r]);
    }
  }
}

// ---------------- fused conv1x1 from y (X8): kv0, kv1, q2 -- one y read ----------------
__global__ __launch_bounds__(256) void k_kvq(const float* __restrict__ yin,
      const float* __restrict__ kvw0, const float* __restrict__ kvw1, const float* __restrict__ qw2,
      __bf16* __restrict__ k0o, __bf16* __restrict__ v0o,
      __bf16* __restrict__ k1o, __bf16* __restrict__ v1o, __bf16* __restrict__ q2o){
  X8_SETUP
  bf16x8 bf[2][8];
  X8_FILL_F32(yin + ibase)
  X8_MM_BF(kvw0,        bf, k0o)
  X8_MM_BF(kvw0 + 4096, bf, v0o)
  X8_MM_BF(kvw1,        bf, k1o)
  X8_MM_BF(kvw1 + 4096, bf, v1o)
  X8_MM_BF(qw2,         bf, q2o)
}

// ---------------- fused comb + refine conv1x1 + kv2 conv1x1 (agg via LDS, never global) ----------------
__global__ __launch_bounds__(256) void k_comb_kvb(const __bf16* __restrict__ lo2, const __bf16* __restrict__ hi2,
        const float* __restrict__ swb, const float* __restrict__ cwv,
        const float* __restrict__ w, const float* __restrict__ bias,
        const float* __restrict__ wkv,
        __bf16* __restrict__ kout, __bf16* __restrict__ vout){
  __shared__ __bf16 aggl[64][514];    // [ch][block-local px], +2 px pad
  X8_SETUP
  int pxl = wvi*128 + 8*lm;           // block-local px base for this lane
  const float* swp = swb + ((i64)b<<16) + p0 + 8*lm;
  float4 sw0 = *(const float4*)swp;
  float4 sw1 = *(const float4*)(swp+4);
  float swv[8] = {sw0.x,sw0.y,sw0.z,sw0.w,sw1.x,sw1.y,sw1.z,sw1.w};
  bf16x8 bf[2][8];
  #pragma unroll
  for (int s=0;s<2;s++){
    #pragma unroll
    for (int j=0;j<8;j++){
      int ch = s*32 + kg*8 + j;
      bf16x8 l8 = *(const bf16x8*)(lo2 + ibase + ((i64)ch<<16) + 8*lm);
      bf16x8 h8 = *(const bf16x8*)(hi2 + ibase + ((i64)ch<<16) + 8*lm);
      float cw = cwv[(b<<6) + ch];
      #pragma unroll
      for (int e=0;e<8;e++) bf[s][e][j] = (__bf16)((float)l8[e]*swv[e] + (float)h8[e]*cw);
    }
  }
  #pragma unroll
  for (int m=0;m<4;m++){
    X8_ACC_M(w, bf)
    #pragma unroll
    for (int r=0;r<4;r++){
      int oc = m*16 + kg*4 + r;
      float bv = bias[oc];
      bf16x8 ov;
      #pragma unroll
      for (int e=0;e<8;e++) ov[e]=(__bf16)(acc[e][r]+bv);
      *(bf16x8*)(&aggl[oc][pxl]) = ov;
    }
  }
  __syncthreads();
  // rebuild B-frags from LDS agg (same wave's px, all 64 ch)
  bf16x8 bf2[2][8];
  #pragma unroll
  for (int s=0;s<2;s++){
    #pragma unroll
    for (int j=0;j<8;j++){
      int ch = s*32 + kg*8 + j;
      bf16x8 u_ = *(const bf16x8*)(&aggl[ch][pxl]);
      #pragma unroll
      for (int e=0;e<8;e++) bf2[s][e][j] = u_[e];
    }
  }
  X8_MM_BF(wkv,        bf2, kout)
  X8_MM_BF(wkv + 4096, bf2, vout)
}

// ---------------- merged mconv hi + lo (double-grid) ----------------
__global__ __launch_bounds__(256) void k_mm_hilo(const __bf16* __restrict__ va, const __bf16* __restrict__ vb,
        const float* __restrict__ M0, const float* __restrict__ M1,
        float* __restrict__ mx, float* __restrict__ mn,
        __bf16* __restrict__ outa, __bf16* __restrict__ outb,
        float* __restrict__ spart, int hgrid){
  __shared__ float ls[4][64], lmx[4][64];
  int bx = blockIdx.x;
  int set = (bx >= hgrid) ? 1 : 0;
  int blk = bx - set*hgrid;
  X8_SETUP_BLK(blk)
  if (set == 0){
    // hi: M0 x va + per-px channel max/mean
    bf16x8 bf[2][8];
    X8_FILL_BF(va + ibase)
    const float* Wb = M0 + ((i64)b<<12);
    float smx[8], ssum[8];
    #pragma unroll
    for (int e=0;e<8;e++){ smx[e]=-1e30f; ssum[e]=0.f; }
    #pragma unroll
    for (int m=0;m<4;m++){
      X8_ACC_M(Wb, bf)
      X8_ST_BF(outa)
      #pragma unroll
      for (int r=0;r<4;r++){
        #pragma unroll
        for (int e=0;e<8;e++){ smx[e]=fmaxf(smx[e],acc[e][r]); ssum[e]+=acc[e][r]; }
      }
    }
    #pragma unroll
    for (int e=0;e<8;e++){
      smx[e] = fmaxf(smx[e], __shfl_xor(smx[e],16));
      smx[e] = fmaxf(smx[e], __shfl_xor(smx[e],32));
      ssum[e] += __shfl_xor(ssum[e],16);
      ssum[e] += __shfl_xor(ssum[e],32);
    }
    if (kg==0){
      i64 pbase = ((i64)b<<16) + p0 + 8*lm;
      *(float4*)(mx+pbase)   = make_float4(smx[0],smx[1],smx[2],smx[3]);
      *(float4*)(mx+pbase+4) = make_float4(smx[4],smx[5],smx[6],smx[7]);
      const float iv = 1.0f/64.0f;
      *(float4*)(mn+pbase)   = make_float4(ssum[0]*iv,ssum[1]*iv,ssum[2]*iv,ssum[3]*iv);
      *(float4*)(mn+pbase+4) = make_float4(ssum[4]*iv,ssum[5]*iv,ssum[6]*iv,ssum[7]*iv);
    }
  } else {
    // lo: M1 x vb + per-channel sum/max partials
    bf16x8 bf[2][8];
    X8_FILL_BF(vb + ibase)
    const float* Wb = M1 + ((i64)b<<12);
    #pragma unroll
    for (int m=0;m<4;m++){
      X8_ACC_M(Wb, bf)
      X8_ST_BF(outb)
      #pragma unroll
      for (int r=0;r<4;r++){
        int oc = m*16 + kg*4 + r;
        float s = 0.f, mm = -1e30f;
        #pragma unroll
        for (int e=0;e<8;e++){ s += acc[e][r]; mm = fmaxf(mm, acc[e][r]); }
        #pragma unroll
        for (int off=8; off; off>>=1){ s += __shfl_xor(s,off); mm = fmaxf(mm,__shfl_xor(mm,off)); }
        if (lm==0){ ls[wvi][oc]=s; lmx[wvi][oc]=mm; }
      }
    }
    __syncthreads();
    if (t<64){
      float s = ls[0][t]+ls[1][t]+ls[2][t]+ls[3][t];
      float mm = fmaxf(fmaxf(lmx[0][t],lmx[1][t]),fmaxf(lmx[2][t],lmx[3][t]));
      spart[(i64)blk*128 + t*2]   = s;
      spart[(i64)blk*128 + t*2+1] = mm;
    }
  }
}

// ---------------- final mconv (X8): M x v, *para1 + y*para2, fp32 out ----------------
__global__ __launch_bounds__(256) void k_mm_fin(const __bf16* __restrict__ v, const float* __restrict__ M,
      const float* __restrict__ para1, const float* __restrict__ para2,
      const float* __restrict__ yin, float* __restrict__ out){
  X8_SETUP
  bf16x8 bf[2][8];
  X8_FILL_BF(v + ibase)
  const float* Wb = M + ((i64)b<<12);
  #pragma unroll
  for (int m=0;m<4;m++){
    X8_ACC_M(Wb, bf)
    #pragma unroll
    for (int r=0;r<4;r++){
      int oc = m*16 + kg*4 + r;
      float p1 = para1[oc], p2 = para2[oc];
      const float* yp = yin + ibase + ((i64)oc<<16) + 8*lm;
      float4 y0 = *(const float4*)yp;
      float4 y1 = *(const float4*)(yp+4);
      float* op = out + ibase + ((i64)oc<<16) + 8*lm;
      *(float4*)op     = make_float4(acc[0][r]*p1+y0.x*p2, acc[1][r]*p1+y0.y*p2,
                                     acc[2][r]*p1+y0.z*p2, acc[3][r]*p1+y0.w*p2);
      *(float4*)(op+4) = make_float4(acc[4][r]*p1+y1.x*p2, acc[5][r]*p1+y1.y*p2,
                                     acc[6][r]*p1+y1.z*p2, acc[7][r]*p1+y1.w*p2);
    }
  }
}

// ---------------- Gram-MFMA stats w/ LDS 2-row staging, merged double-set dispatch ----------------
__global__ __launch_bounds__(256) void k_gram(const __bf16* __restrict__ q0, const __bf16* __restrict__ kk0,
        const __bf16* __restrict__ q1, const __bf16* __restrict__ kk1,
        const float* __restrict__ qdw0, const float* __restrict__ kdw0,
        const float* __restrict__ qdw1, const float* __restrict__ kdw1,
        float* __restrict__ part, int hgrid){
  __shared__ __bf16 lds[2][2][16][264];
  __shared__ float red[4][16][16];
  int bx = blockIdx.x;
  int set = (bx >= hgrid) ? 1 : 0;
  int blk = bx - set*hgrid;
  const __bf16* qpre = set ? q1 : q0;
  const __bf16* kpre = set ? kk1 : kk0;
  const float* qdw = set ? qdw1 : qdw0;
  const float* kdw = set ? kdw1 : kdw0;
  float* ppart = part + (i64)set*hgrid*80;
  int rowblk = blk & 15;
  int bh = blk >> 4;
  int h = bh & 7, b = bh >> 3;
  int t = threadIdx.x;
  int lane = t & 63, wvi = t >> 6;
  int lm = lane & 15, kg = lane >> 4;
  const float* wp = (lm < 8 ? qdw : kdw) + h*72 + (lm&7)*9;
  float w0=wp[0],w1=wp[1],w2=wp[2],w3=wp[3],w4=wp[4],w5=wp[5],w6=wp[6],w7=wp[7],w8=wp[8];
  int p = t >> 4, seg = t & 15;
  const __bf16* plbase = (p < 8 ? qpre : kpre) + (((i64)((b<<6)+(h<<3)+(p&7)))<<16);
  int R0 = rowblk*16;

  float h0c[2][8], h1c[2][8];
  #pragma unroll
  for (int cc=0;cc<2;cc++)
    #pragma unroll
    for (int e=0;e<8;e++){ h0c[cc][e]=0.f; h1c[cc][e]=0.f; }
  f32x4 acc = {0.f,0.f,0.f,0.f};

  auto stage2 = [&](int bi, int ir){
    #pragma unroll
    for (int rr=0;rr<2;rr++){
      int r_ = ir + rr;
      __bf16* dst = &lds[bi][rr][p][seg*16];
      if ((unsigned)r_ < 256u){
        const __bf16* src = plbase + r_*256 + seg*16;
        bf16x8 a = *(const bf16x8*)src;
        bf16x8 c = *(const bf16x8*)(src+8);
        *(bf16x8*)dst = a; *(bf16x8*)(dst+8) = c;
      } else {
        bf16x8 z = {};
        *(bf16x8*)dst = z; *(bf16x8*)(dst+8) = z;
      }
    }
  };

  stage2(0, R0-1);
  __syncthreads();
  int buf = 0;
  for (int pr = 0; pr < 9; pr++){
    int irbase = R0-1 + 2*pr;
    if (pr < 8) stage2(buf^1, irbase+2);
    #pragma unroll
    for (int rr=0;rr<2;rr++){
      int ir = irbase + rr;
      const __bf16* rowp = &lds[buf][rr][lm][0];
      #pragma unroll
      for (int cc=0; cc<2; cc++){
        int xb = (wvi*2 + cc)*32 + kg*8;
        bf16x8 mid = *(const bf16x8*)(rowp + xb);
        float win[10];
        win[0] = (xb==0)   ? 0.f : (float)rowp[xb-1];
        #pragma unroll
        for (int w=1; w<9; w++) win[w] = (float)mid[w-1];
        win[9] = (xb==248) ? 0.f : (float)rowp[xb+8];
        float o[8];
        #pragma unroll
        for (int e=0;e<8;e++){
          float t0 = w0*win[e] + w1*win[e+1] + w2*win[e+2];
          float t1 = w3*win[e] + w4*win[e+1] + w5*win[e+2];
          float t2 = w6*win[e] + w7*win[e+1] + w8*win[e+2];
          o[e] = h0c[cc][e] + t2;
          h0c[cc][e] = h1c[cc][e] + t1;
          h1c[cc][e] = t0;
        }
        if (ir > R0){
          bf16x8 xf;
          #pragma unroll
          for (int e=0;e<8;e++) xf[e] = (__bf16)o[e];
          acc = MFMA16(xf, xf, acc);
        }
      }
    }
    __syncthreads();
    buf ^= 1;
  }
  #pragma unroll
  for (int r=0;r<4;r++) red[wvi][kg*4+r][lm] = acc[r];
  __syncthreads();
  if (t < 80){
    int r, c;
    if (t < 64){ r = t>>3; c = 8 + (t&7); }
    else if (t < 72){ r = t-64; c = r; }
    else { r = 8 + (t-72); c = r; }
    float s = red[0][r][c]+red[1][r][c]+red[2][r][c]+red[3][r][c];
    ppart[(i64)blk*80 + t] = s;
  }
}

__global__ __launch_bounds__(128) void k_stats_fin(const float* __restrict__ part, float* __restrict__ stats){
  int bh = blockIdx.x; int t = threadIdx.x;
  if (t < 80){
    float s=0.f;
    for (int c=0;c<NCHUNK;c++) s += part[((i64)bh*NCHUNK+c)*80 + t];
    stats[bh*80+t] = s;
  }
}

// ---------------- softmax + fold attn into 64x64 M (merged: super-b over 2 sets) ----------------
__global__ __launch_bounds__(64) void k_attn_m(const float* __restrict__ stats, const float* __restrict__ temp,
                         const float* __restrict__ projw, float* __restrict__ M, int nb){
  __shared__ float attn[8][8][8];
  int bsup = blockIdx.x; int t = threadIdx.x;
  int set = (bsup >= nb) ? 1 : 0;
  int h = t >> 3, cc = t & 7;
  const float* st = stats + (bsup*8+h)*80;
  float nq = fmaxf(sqrtf(st[64+cc]), 1e-12f);
  float tmp = temp[set*8 + h];
  const float* pw = projw + set*4096;
  float s[8];
  float mx = -1e30f;
  #pragma unroll
  for (int d=0;d<8;d++){
    float nk = fmaxf(sqrtf(st[72+d]), 1e-12f);
    s[d] = st[cc*8+d]/(nq*nk)*tmp;
    mx = fmaxf(mx, s[d]);
  }
  float sum=0.f;
  #pragma unroll
  for (int d=0;d<8;d++){ s[d]=expf(s[d]-mx); sum+=s[d]; }
  float inv = 1.0f/sum;
  #pragma unroll
  for (int d=0;d<8;d++) attn[h][cc][d] = s[d]*inv;
  __syncthreads();
  int o = t;
  for (int hh=0; hh<8; hh++){
    #pragma unroll
    for (int d=0; d<8; d++){
      float acc=0.f;
      #pragma unroll
      for (int c2=0;c2<8;c2++) acc += pw[o*64 + hh*8 + c2]*attn[hh][c2][d];
      M[((i64)bsup*64 + o)*64 + hh*8 + d] = acc;
    }
  }
}

// ---------------- depthwise 3x3 (v path), merged double-set dispatch ----------------
__global__ __launch_bounds__(256) void k_dwb(const __bf16* __restrict__ in0, const __bf16* __restrict__ in1,
        const float* __restrict__ wd0, const float* __restrict__ wd1,
        __bf16* __restrict__ out0, __bf16* __restrict__ out1, int hgrid){
  int bx = blockIdx.x;
  int set = (bx >= hgrid) ? 1 : 0;
  int blk = bx - set*hgrid;
  const __bf16* in = set ? in1 : in0;
  const float* wd = set ? wd1 : wd0;
  __bf16* out = set ? out1 : out0;
  int half = blk & 1; int c = (blk>>1)&63; int b = blk>>7;
  int t = threadIdx.x;
  int strip = t & 31, rg = t >> 5;
  const __bf16* ip = in + (((i64)((b<<6)+c))<<16);
  __bf16* op = out + (((i64)((b<<6)+c))<<16);
  const float* wp = wd + c*9;
  float w0=wp[0],w1=wp[1],w2=wp[2],w3=wp[3],w4=wp[4],w5=wp[5],w6=wp[6],w7=wp[7],w8=wp[8];
  int R0 = half*128 + rg*16;
  int xb = strip*8;
  bool left = (xb==0), right = (xb==248);
  float h0[8], h1[8];
  #pragma unroll
  for (int e=0;e<8;e++){ h0[e]=0.f; h1[e]=0.f; }
  for (int ir = R0-1; ir <= R0+16; ir++){
    bool rok = ((unsigned)ir < 256u);
    float win[10];
    if (rok){
      const __bf16* rp = ip + ir*256 + xb;
      bf16x8 mid = *(const bf16x8*)rp;
      win[0] = left ? 0.f : (float)rp[-1];
      #pragma unroll
      for (int w=1; w<9; w++) win[w] = (float)mid[w-1];
      win[9] = right ? 0.f : (float)rp[8];
    } else {
      #pragma unroll
      for (int w=0; w<10; w++) win[w] = 0.f;
    }
    float o[8];
    #pragma unroll
    for (int e=0;e<8;e++){
      float t0 = w0*win[e] + w1*win[e+1] + w2*win[e+2];
      float t1 = w3*win[e] + w4*win[e+1] + w5*win[e+2];
      float t2 = w6*win[e] + w7*win[e+1] + w8*win[e+2];
      o[e] = h0[e] + t2;
      h0[e] = h1[e] + t1;
      h1[e] = t0;
    }
    if (ir > R0){
      bf16x8 ov;
      #pragma unroll
      for (int e=0;e<8;e++) ov[e] = (__bf16)o[e];
      *(bf16x8*)(op + (ir-1)*256 + xb) = ov;
    }
  }
}

// ---------------- fused spatfin + cw: per-batch channel stats reduce + gate MLP ----------------
__global__ __launch_bounds__(64) void k_spatcw(const float* __restrict__ spart,
                     const float* __restrict__ w1, const float* __restrict__ w2, float* __restrict__ cw){
  __shared__ float lm_[64], lx_[64];
  __shared__ float ha[4], hm[4];
  int b = blockIdx.x; int c = threadIdx.x;
  float s=0.f, m=-1e30f;
  for (int r=0;r<128;r++){
    s += spart[(i64)(b*128+r)*128 + c*2];
    m = fmaxf(m, spart[(i64)(b*128+r)*128 + c*2+1]);
  }
  lm_[c] = s*(1.0f/65536.0f);
  lx_[c] = m;
  __syncthreads();
  if (c < 4){
    float sa=0.f, sm_=0.f;
    for (int j=0;j<64;j++){ sa += w1[c*64+j]*lm_[j]; sm_ += w1[c*64+j]*lx_[j]; }
    ha[c] = fmaxf(sa, 0.f); hm[c] = fmaxf(sm_, 0.f);
  }
  __syncthreads();
  float a=0.f;
  #pragma unroll
  for (int j=0;j<4;j++) a += w2[c*4+j]*(ha[j]+hm[j]);
  cw[b*64+c] = sigm(a);
}

__global__ __launch_bounds__(256) void k_sw(const float* __restrict__ mx, const float* __restrict__ mn,
                     const float* __restrict__ w, float* __restrict__ sw){
  int row = blockIdx.x & 255; int b = blockIdx.x >> 8; int t = threadIdx.x;
  const float* m0 = mx + ((i64)b<<16);
  const float* m1 = mn + ((i64)b<<16);
  float acc=0.f;
  for (int ky=0;ky<7;ky++){
    int yy = row+ky-3; if ((unsigned)yy>255u) continue;
    for (int kx=0;kx<7;kx++){
      int xx = t+kx-3; if ((unsigned)xx>255u) continue;
      acc += w[ky*7+kx]*m0[yy*256+xx] + w[49+ky*7+kx]*m1[yy*256+xx];
    }
  }
  sw[((i64)b<<16) + row*256 + t] = sigm(acc);
}

// =====================================================================================
extern "C" void kernel_launch(void* const* d_in, const int* in_sizes, int n_in,
                              void* d_out, int out_size, void* d_ws, size_t ws_size,
                              hipStream_t stream){
  const float* x      = (const float*)d_in[0];
  const float* y      = (const float*)d_in[1];
  const float* conv1w = (const float*)d_in[2];
  const float* ratew1 = (const float*)d_in[3];
  const float* ratew2 = (const float*)d_in[4];
  const float* temp   = (const float*)d_in[5];
  const float* qw     = (const float*)d_in[6];
  const float* qdw    = (const float*)d_in[7];
  const float* kvw    = (const float*)d_in[8];
  const float* kvdw   = (const float*)d_in[9];
  const float* projw  = (const float*)d_in[10];
  const float* spw    = (const float*)d_in[11];
  const float* cgw1   = (const float*)d_in[12];
  const float* cgw2   = (const float*)d_in[13];
  const float* rprojw = (const float*)d_in[14];
  const float* rprojb = (const float*)d_in[15];
  const float* para1  = (const float*)d_in[16];
  const float* para2  = (const float*)d_in[17];
  float* D = (float*)d_out;

  // pick largest batch-group size whose footprint fits: 3 big units + pool
  int nb = 8;
  for (;;){
    size_t unit = (size_t)nb*64*HW_;
    size_t pool = (size_t)nb*3*HW_            // Rbuf
                + (size_t)nb*512 + (size_t)nb*64 + 64
                + 2*(size_t)nb*8*NCHUNK*80    // part (2 sets)
                + 2*(size_t)nb*8*80           // stats (2 sets)
                + 2*(size_t)nb*64*64          // M (2 sets)
                + 3*(size_t)nb*HW_            // mxmap, mnmap, swb
                + (size_t)nb*128*128          // spart
                + (size_t)nb*64;              // cwb
    if ((3*unit + pool)*sizeof(float) <= ws_size || nb==1) break;
    nb >>= 1;
  }

  size_t unit = (size_t)nb*64*HW_;
  float* U0 = (float*)d_ws;
  float* U1 = U0 + unit;
  float* U2 = U1 + unit;
  float* sm = U2 + unit;
  float* Rbuf  = sm;  sm += (size_t)nb*3*HW_;
  float* coeff = sm;  sm += (size_t)nb*512;
  float* pooled= sm;  sm += (size_t)nb*64;
  float* flagb = sm;  sm += 64;
  float* part  = sm;  sm += 2*(size_t)nb*8*NCHUNK*80;
  float* stats = sm;  sm += 2*(size_t)nb*8*80;
  float* Mb    = sm;  sm += 2*(size_t)nb*64*64;
  float* mxmap = sm;  sm += (size_t)nb*HW_;
  float* mnmap = sm;  sm += (size_t)nb*HW_;
  float* swb   = sm;  sm += (size_t)nb*HW_;
  float* spart = sm;  sm += (size_t)nb*128*128;
  float* cwb   = sm;  sm += (size_t)nb*64;

  int hgr = nb*8*NCHUNK;     // gram half-grid
  int hdw = nb*128;          // dwb half-grid
  int hmm = nb*128;          // X8 half-grid

  for (int b0 = 0; b0 < 8; b0 += nb){
    const float* yg = y + (i64)b0*64*HW_;
    float*       Dg = D + (i64)b0*64*HW_;
    // bf16 tensor slots: each fp32 unit region holds TWO bf16 tensors of `unit` elements.
    __bf16* U0a = (__bf16*)U0; __bf16* U0c = U0a + unit;
    __bf16* U1a = (__bf16*)U1; __bf16* U1c = U1a + unit;
    __bf16* U2a = (__bf16*)U2; __bf16* U2c = U2a + unit;
    __bf16* Dga = (__bf16*)Dg; __bf16* Dgc = Dga + unit;
    float* Mb1 = Mb + (i64)nb*4096;

    // frontend (xc bf16 in U0a)
    k_resize <<<nb*3*256, 256,0,stream>>>(x, Rbuf, b0);
    k_conv3  <<<nb*256,   256,0,stream>>>(Rbuf, conv1w, U0a);          // xc = U0a (bf16)
    k_dft    <<<nb*64,    256,0,stream>>>(U0a, coeff, pooled);
    k_thr    <<<nb,       64, 0,stream>>>(pooled, ratew1, ratew2, flagb);

    // fused q-recon (cca0-high + cca1-low); xc dead after
    k_convq2 <<<nb*256,256,0,stream>>>(U0a, coeff, flagb, qw + 0*4096, qw + 1*4096, U1a, U1c); // qh=U1a, ql=U1c
    // fused y-matmuls (X8): kv0, kv1, q2-pre
    k_kvq    <<<nb*128,256,0,stream>>>(yg, kvw + 0*8192, kvw + 1*8192, qw + 2*4096,
                                       U2a, Dga, U2c, Dgc, U0c);       // k0,v0,k1,v1,q2

    // merged cca0+cca1 stats pipeline
    k_gram   <<<2*hgr,256,0,stream>>>(U1a, U2a, U1c, U2c,
                                      qdw + 0*576, kvdw + 0*1152, qdw + 1*576, kvdw + 1*1152,
                                      part, hgr);                      // [qh,ql,k0,k1 dead]
    k_stats_fin<<<2*nb*8, 128,0,stream>>>(part, stats);
    k_dwb    <<<2*hdw,256,0,stream>>>(Dga, Dgc, kvdw + 0*1152 + 576, kvdw + 1*1152 + 576,
                                      U1a, U1c, hdw);                  // v0'=U1a, v1'=U1c [v0,v1 dead]
    k_attn_m <<<2*nb, 64,0,stream>>>(stats, temp, projw, Mb, nb);      // Mb0, Mb1

    // merged hi+lo
    k_mm_hilo<<<2*hmm,256,0,stream>>>(U1a, U1c, Mb, Mb1, mxmap, mnmap, Dga, Dgc, spart, hmm);
                                                                       // high2=Dga, low2=Dgc

    // refine weights
    k_spatcw  <<<nb,     64, 0,stream>>>(spart, cgw1, cgw2, cwb);
    k_sw      <<<nb*256, 256,0,stream>>>(mxmap, mnmap, spw, swb);

    // fused comb + refine-proj + kv2 (agg via LDS, never global)
    k_comb_kvb<<<nb*128,256,0,stream>>>(Dgc, Dga, swb, cwb, rprojw, rprojb,
                                        kvw + 2*8192, U2a, U2c);       // k2=U2a, v2=U2c

    // cca2 (q2=U0c)
    k_gram   <<<hgr,256,0,stream>>>(U0c, U2a, U0c, U2a,
                                    qdw + 2*576, kvdw + 2*1152, qdw + 2*576, kvdw + 2*1152,
                                    part, hgr);
    k_stats_fin<<<nb*8, 128,0,stream>>>(part, stats);
    k_dwb    <<<hdw,256,0,stream>>>(U2c, U2c, kvdw + 2*1152 + 576, kvdw + 2*1152 + 576,
                                    U1a, U1a, hdw);                    // v'=U1a
    k_attn_m <<<nb, 64,0,stream>>>(stats, temp + 2*8, projw + 2*4096, Mb, nb);
    k_mm_fin <<<nb*128,256,0,stream>>>(U1a, Mb, para1, para2, yg, Dg); // out fp32
  }
}